// Round 5
// baseline (496.092 us; speedup 1.0000x reference)
//
#include <hip/hip_runtime.h>
#include <stdint.h>

// Problem constants (fixed by the reference): B=2, S=2048, D=2048, Dh=64, Hq=32, Hkv=8, G=4.
#define S_LEN   2048
#define D_MODEL 2048
#define DKV     512

typedef __attribute__((ext_vector_type(8))) short short8;   // 8 x bf16
typedef __attribute__((ext_vector_type(4))) float f32x4;
typedef __attribute__((ext_vector_type(4))) unsigned uint4v;

__device__ static inline unsigned short f2bf(float f) {     // RNE float->bf16 (finite values)
  unsigned u = __builtin_bit_cast(unsigned, f);
  u += 0x7FFFu + ((u >> 16) & 1u);
  return (unsigned short)(u >> 16);
}
__device__ static inline float bf2f(unsigned short h) {
  return __builtin_bit_cast(float, ((unsigned)h) << 16);
}
// pack hi16(f0), hi16(f1) -> one dword (bf16 truncation; 1 v_perm_b32)
__device__ static inline unsigned packtrunc2(float f0, float f1) {
  return __builtin_amdgcn_perm(__builtin_bit_cast(unsigned, f1),
                               __builtin_bit_cast(unsigned, f0), 0x07060302u);
}

__device__ static inline void gload_lds16(const void* g, void* lds) {
  __builtin_amdgcn_global_load_lds((const __attribute__((address_space(1))) void*)g,
                                   (__attribute__((address_space(3))) void*)lds,
                                   16, 0, 0);
}

template <int N>
__device__ __forceinline__ void wait_vm() {
  if constexpr (N == 8)      asm volatile("s_waitcnt vmcnt(8)" ::: "memory");
  else if constexpr (N == 6) asm volatile("s_waitcnt vmcnt(6)" ::: "memory");
  else if constexpr (N == 4) asm volatile("s_waitcnt vmcnt(4)" ::: "memory");
  else if constexpr (N == 3) asm volatile("s_waitcnt vmcnt(3)" ::: "memory");
  else                       asm volatile("s_waitcnt vmcnt(0)" ::: "memory");
}

// gfx950 conditional-exchange primitives (register-pair <-> lane-half swaps):
__device__ static inline void pl32swap(unsigned& a, unsigned& b) {
  asm volatile("v_permlane32_swap_b32 %0, %1" : "+v"(a), "+v"(b));
}
__device__ static inline void pl16swap(unsigned& a, unsigned& b) {
  asm volatile("v_permlane16_swap_b32 %0, %1" : "+v"(a), "+v"(b));
}

// fp32 -> bf16 bulk conversion for all 5 inputs in ONE launch (exact region split, units of 8 floats).
__global__ __launch_bounds__(256) void cvt_all_kernel(
    const float* __restrict__ x, const float* __restrict__ wq, const float* __restrict__ wk,
    const float* __restrict__ wv, const float* __restrict__ wo,
    unsigned short* __restrict__ xb, unsigned short* __restrict__ wqb,
    unsigned short* __restrict__ wkb, unsigned short* __restrict__ wvb,
    unsigned short* __restrict__ wob) {
  int i = blockIdx.x * 256 + threadIdx.x;          // 0 .. 2359296-1
  const float* s; unsigned short* d;
  if (i < 1048576)      { s = x;  d = xb;  }
  else if (i < 1572864) { s = wq; d = wqb; i -= 1048576; }
  else if (i < 1703936) { s = wk; d = wkb; i -= 1572864; }
  else if (i < 1835008) { s = wv; d = wvb; i -= 1703936; }
  else                  { s = wo; d = wob; i -= 1835008; }
  const float4 a = ((const float4*)s)[i * 2];
  const float4 b = ((const float4*)s)[i * 2 + 1];
  unsigned short u[8] = {f2bf(a.x), f2bf(a.y), f2bf(a.z), f2bf(a.w),
                         f2bf(b.x), f2bf(b.y), f2bf(b.z), f2bf(b.w)};
  *(uint4*)(d + (size_t)i * 8) = *(const uint4*)u;
}

// ---------------------------------------------------------------------------------------------
// Deep-pipelined GEMM: C(M,N) = A(M,K=2048) @ B(N,K)^T, bf16 inputs.  (unchanged from R1)
// ---------------------------------------------------------------------------------------------
template <int BM, int CMODE, typename CT>
__device__ __forceinline__ void gemm_deep_body(
    const unsigned short* __restrict__ A, int lda,
    const unsigned short* __restrict__ B, int ldb,
    CT* __restrict__ C, int ldc, int m0, int n0, unsigned short* ldsu) {
  constexpr int MI = BM / 32;             // 8 (BM=256) or 4 (BM=128)
  constexpr int NI = 4;
  constexpr int A_BYTES = BM * 64;        // BM*32*2B : 16KB or 8KB
  constexpr int B_BYTES = 256 * 64;       // 16KB
  constexpr int TILE_BYTES = A_BYTES + B_BYTES;
  constexpr int AL = BM / 128;            // A stage-loads per thread per phase: 2 or 1
  constexpr int LOADS = AL + 2;           // total stage-loads/thread/phase: 4 or 3
  constexpr int VMS = 2 * LOADS;          // steady-state vmcnt (retire 3-phases-old tile)

  const int tid  = threadIdx.x;
  const int lane = tid & 63;
  const int w    = tid >> 6;              // 0..7
  const int wm   = w >> 2;                // 0..1  (M halves)
  const int wn   = w & 3;                 // 0..3  (N quarters)
  const int lcol = lane & 15;
  const int lq   = lane >> 4;
  char* const ldsb = (char*)ldsu;

  // ---- staging lane constants (inverse swizzle on the global side) ----
  const int sl   = (lane & 7) ^ (lane >> 3);   // logical slab this lane must fetch
  const int colg = (sl & 3) * 8;               // element col within the 32-wide K-tile
  const unsigned short* gA[AL];
  const unsigned short* gB[2];
#pragma unroll
  for (int L = 0; L < AL; ++L) {
    const int r = 2 * (L * 64 + w * 8 + (lane >> 3)) + (sl >> 2);
    gA[L] = A + (size_t)(m0 + r) * lda + colg;
  }
#pragma unroll
  for (int L = 0; L < 2; ++L) {
    const int r = 2 * (L * 64 + w * 8 + (lane >> 3)) + (sl >> 2);
    gB[L] = B + (size_t)(n0 + r) * ldb + colg;
  }

  auto stage = [&](int tt) {
    char* const sb = ldsb + (tt & 3) * TILE_BYTES;
#pragma unroll
    for (int L = 0; L < AL; ++L)
      gload_lds16(gA[L] + tt * 32, sb + L * 8192 + w * 1024);
#pragma unroll
    for (int L = 0; L < 2; ++L)
      gload_lds16(gB[L] + tt * 32, sb + A_BYTES + L * 8192 + w * 1024);
  };

  // ---- fragment-read lane constant (swizzled) ----
  const int sR    = (((lcol & 1) << 2) | lq) ^ ((lcol >> 1) & 7);
  const int rdoff = (lcol >> 1) * 128 + sR * 16;

  f32x4 acc[MI][NI] = {};

  auto compute_tile = [&](char* buf) {
    short8 af[MI], bfr[NI];
#pragma unroll
    for (int mi = 0; mi < MI; ++mi)
      af[mi] = *(const short8*)(buf + wm * (MI * 1024) + mi * 1024 + rdoff);
#pragma unroll
    for (int ni = 0; ni < NI; ++ni)
      bfr[ni] = *(const short8*)(buf + A_BYTES + wn * 4096 + ni * 1024 + rdoff);
    __builtin_amdgcn_s_setprio(1);
#pragma unroll
    for (int mi = 0; mi < MI; ++mi)
#pragma unroll
      for (int ni = 0; ni < NI; ++ni)
        acc[mi][ni] = __builtin_amdgcn_mfma_f32_16x16x32_bf16(af[mi], bfr[ni], acc[mi][ni], 0, 0, 0);
    __builtin_amdgcn_s_setprio(0);
  };

  // prologue: 3 tiles in flight
  stage(0); stage(1); stage(2);

#define GPHASE(T, VMW, DOSTG)                          \
  do {                                                 \
    wait_vm<VMW>();                                    \
    __builtin_amdgcn_s_barrier();                      \
    asm volatile("" ::: "memory");                     \
    __builtin_amdgcn_sched_barrier(0);                 \
    if (DOSTG) stage((T) + 3);                         \
    compute_tile(ldsb + ((T) & 3) * TILE_BYTES);       \
  } while (0)

  for (int t4 = 0; t4 < 15; ++t4) {
    const int t = t4 * 4;
    GPHASE(t + 0, VMS, true);
    GPHASE(t + 1, VMS, true);
    GPHASE(t + 2, VMS, true);
    GPHASE(t + 3, VMS, true);
  }
  GPHASE(60, VMS,   true);
  GPHASE(61, VMS,   false);
  GPHASE(62, LOADS, false);
  GPHASE(63, 0,     false);
#undef GPHASE

  // epilogue (m97-verified C/D mapping, generalized)
#pragma unroll
  for (int mi = 0; mi < MI; ++mi)
#pragma unroll
    for (int ni = 0; ni < NI; ++ni)
#pragma unroll
      for (int r = 0; r < 4; ++r) {
        const int row = m0 + wm * (MI * 16) + mi * 16 + lq * 4 + r;
        const int col = n0 + wn * 64 + ni * 16 + lcol;
        if constexpr (CMODE == 1) {
          C[((size_t)((row >> 11) * 512 + col)) * 2048 + (row & 2047)] = f2bf(acc[mi][ni][r]);
        } else if constexpr (CMODE == 2) {
          C[(size_t)row * ldc + col] = acc[mi][ni][r];
        } else {
          C[(size_t)row * ldc + col] = f2bf(acc[mi][ni][r]);
        }
      }
}

// Fused QKV projection: 192 blocks (16 M-tiles x [8 Q + 2 K + 2 V] N-tiles), 512 thr, 128KB LDS.
__global__ __launch_bounds__(512, 2) void qkv_gemm_kernel(
    const unsigned short* __restrict__ x,
    const unsigned short* __restrict__ Wq, const unsigned short* __restrict__ Wk,
    const unsigned short* __restrict__ Wv,
    unsigned short* __restrict__ Qo, unsigned short* __restrict__ Ko,
    unsigned short* __restrict__ Vt) {
  extern __shared__ __align__(16) unsigned short lds[];
  const int bid = blockIdx.x;                   // 192 = 8 XCDs * 24
  const int swz = (bid & 7) * 24 + (bid >> 3);  // bijective XCD swizzle (192 % 8 == 0)
  const int mt = swz / 12, nt = swz % 12;
  const int m0 = mt * 256;
  if (nt < 8)
    gemm_deep_body<256, 0, unsigned short>(x, D_MODEL, Wq, D_MODEL, Qo, D_MODEL, m0, nt * 256, lds);
  else if (nt < 10)
    gemm_deep_body<256, 0, unsigned short>(x, D_MODEL, Wk, D_MODEL, Ko, DKV, m0, (nt - 8) * 256, lds);
  else
    gemm_deep_body<256, 1, unsigned short>(x, D_MODEL, Wv, D_MODEL, Vt, DKV, m0, (nt - 10) * 256, lds);
}

// O-projection: bf16 A (attn out) x bf16 Wo -> fp32 out. 256 blocks (32 x 8) = exact CU fill.
__global__ __launch_bounds__(512, 2) void oproj_gemm_kernel(
    const unsigned short* __restrict__ A, const unsigned short* __restrict__ Wo,
    float* __restrict__ C) {
  extern __shared__ __align__(16) unsigned short lds[];
  const int bid = blockIdx.x;                   // 256 = 8 XCDs * 32
  const int swz = (bid & 7) * 32 + (bid >> 3);
  const int mt = swz >> 3, nt = swz & 7;
  gemm_deep_body<128, 2, float>(A, D_MODEL, Wo, D_MODEL, C, D_MODEL, mt * 128, nt * 256, lds);
}

// RoPE in-place on ws Q and K in ONE launch (row = b*S+s, col = h*64+d; interleaved pairs).
// Q scale folds 1/sqrt(Dh)*log2(e) = 0.125*1.442695 (log2-domain softmax downstream).
__global__ __launch_bounds__(256) void rope_both_kernel(unsigned short* __restrict__ Qb,
                                                        unsigned short* __restrict__ Kb) {
  int idx = blockIdx.x * 256 + threadIdx.x;       // 0 .. 5242879
  unsigned short* X; int lgHalf; float scale;
  if (idx < 4194304) { X = Qb; lgHalf = 10; scale = 0.1803368801111244f; }
  else               { X = Kb; lgHalf = 8;  scale = 1.0f; idx -= 4194304; }
  const int half = 1 << lgHalf;
  const int r  = idx >> lgHalf;
  const int cp = idx & (half - 1);
  const int i  = cp & 31;
  const int s  = r & (S_LEN - 1);
  const float inv = exp2f(-13.287712379549449f * (float)(2 * i) * (1.0f / 64.0f)); // 10000^(-2i/64)
  const float th  = (float)s * inv;
  const float c = cosf(th), sn = sinf(th);
  unsigned short* p = X + ((size_t)r << (lgHalf + 1)) + 2 * cp;
  const float x0 = bf2f(p[0]), x1 = bf2f(p[1]);
  p[0] = f2bf((x0 * c - x1 * sn) * scale);
  p[1] = f2bf((x0 * sn + x1 * c) * scale);
}

// ---------------------------------------------------------------------------------------------
// Flash attention (R5 = exact R3 body @ 4 blocks/CU + setprio):
//  - R3 structure (proven 92 VGPR, no spill, passed): transposed scores, in-register P
//    redistribution (4 pl32swap + 4 pl16swap), K/V double-buffered LDS, ONE raw barrier/iter.
//  - ONLY changes vs R3:
//    (a) __launch_bounds__(256, 4): min-waves attr gates blocks/CU (R2: 4->occ 40%;
//        R3: 2->occ 19%). 4 blocks/CU = 16 waves/CU; LDS 4x36.9 = 147.5KB <= 160KB;
//        VGPR cap 128 >= R3's measured 92 -> no spill expected.
//    (b) s_setprio(1/0) around S- and O-MFMA clusters (T5: +4-7% attn when waves are at
//        different phases; with 4 unsynced blocks/CU the mechanism applies).
//  - R4's deferred-PV is DROPPED (spilled: VGPR 84 + 19MB scratch writes at min=3).
// ---------------------------------------------------------------------------------------------
#define SOFTMAX_FRAG(Sv, lac, pf)                                              \
  do {                                                                         \
    float e0 = __builtin_amdgcn_exp2f(Sv[0][0]);                               \
    float e1 = __builtin_amdgcn_exp2f(Sv[0][1]);                               \
    float e2 = __builtin_amdgcn_exp2f(Sv[0][2]);                               \
    float e3 = __builtin_amdgcn_exp2f(Sv[0][3]);                               \
    unsigned dd0 = packtrunc2(e0, e1), dd1 = packtrunc2(e2, e3);               \
    lac += (e0 + e1) + (e2 + e3);                                              \
    e0 = __builtin_amdgcn_exp2f(Sv[1][0]);                                     \
    e1 = __builtin_amdgcn_exp2f(Sv[1][1]);                                     \
    e2 = __builtin_amdgcn_exp2f(Sv[1][2]);                                     \
    e3 = __builtin_amdgcn_exp2f(Sv[1][3]);                                     \
    unsigned dd2 = packtrunc2(e0, e1), dd3 = packtrunc2(e2, e3);               \
    lac += (e0 + e1) + (e2 + e3);                                              \
    e0 = __builtin_amdgcn_exp2f(Sv[2][0]);                                     \
    e1 = __builtin_amdgcn_exp2f(Sv[2][1]);                                     \
    e2 = __builtin_amdgcn_exp2f(Sv[2][2]);                                     \
    e3 = __builtin_amdgcn_exp2f(Sv[2][3]);                                     \
    unsigned dd4 = packtrunc2(e0, e1), dd5 = packtrunc2(e2, e3);               \
    lac += (e0 + e1) + (e2 + e3);                                              \
    e0 = __builtin_amdgcn_exp2f(Sv[3][0]);                                     \
    e1 = __builtin_amdgcn_exp2f(Sv[3][1]);                                     \
    e2 = __builtin_amdgcn_exp2f(Sv[3][2]);                                     \
    e3 = __builtin_amdgcn_exp2f(Sv[3][3]);                                     \
    unsigned dd6 = packtrunc2(e0, e1), dd7 = packtrunc2(e2, e3);               \
    lac += (e0 + e1) + (e2 + e3);                                              \
    pl32swap(dd0, dd2); pl32swap(dd1, dd3);                                    \
    pl32swap(dd4, dd6); pl32swap(dd5, dd7);                                    \
    pl16swap(dd0, dd2); pl16swap(dd1, dd3);                                    \
    pl16swap(dd4, dd6); pl16swap(dd5, dd7);                                    \
    const uint4v va_ = {dd0, dd1, dd2, dd3};                                   \
    const uint4v vb_ = {dd4, dd5, dd6, dd7};                                   \
    pf##0 = __builtin_bit_cast(short8, va_);                                   \
    pf##1 = __builtin_bit_cast(short8, vb_);                                   \
  } while (0)

__global__ __launch_bounds__(256, 4) void attn_kernel(const unsigned short* __restrict__ Q,
                                                      const unsigned short* __restrict__ K,
                                                      const unsigned short* __restrict__ Vt,
                                                      unsigned short* __restrict__ O) {
  const int hq = blockIdx.y;
  const int bb = blockIdx.z;
  const int hk = hq >> 2;
  const int tid  = threadIdx.x;
  const int lane = tid & 63;
  const int w    = tid >> 6;
  const int lcol = lane & 15;
  const int lq   = lane >> 4;
  const int trow = tid >> 2;            // staging row 0..63
  const int tq   = (tid & 3) * 16;      // staging col quarter (16 elems = 32B)

  const int X   = blockIdx.x;           // 0..15
  const int qt0 = X, qt1 = 31 - X;      // ascending; updates = (X+1)+(32-X) = 33 uniform

  // 72-elem rows (144B): 16B-aligned, 2-way bank aliasing on b128 ops (free, m136).
  __shared__ unsigned short Ks[2][64 * 72];
  __shared__ unsigned short Vts[2][64 * 72];

  const int prow = w * 16 + lcol;       // this lane's q-row within a 64-row tile

  // ---- Q fragments direct from global: B-frag n=prow, k = ks*32+lq*8 (16B contiguous) ----
  short8 qf00, qf01, qf10, qf11;
  {
    const unsigned short* g0 = Q + ((size_t)(bb * S_LEN + qt0 * 64 + prow)) * D_MODEL + hq * 64;
    const unsigned short* g1 = Q + ((size_t)(bb * S_LEN + qt1 * 64 + prow)) * D_MODEL + hq * 64;
    qf00 = *(const short8*)(g0 + lq * 8);
    qf01 = *(const short8*)(g0 + 32 + lq * 8);
    qf10 = *(const short8*)(g1 + lq * 8);
    qf11 = *(const short8*)(g1 + 32 + lq * 8);
  }

  // ---- prefetch K/V tile 0 into registers ----
  uint4 kp0, kp1, vp0, vp1;
  {
    const unsigned short* gk = K + ((size_t)(bb * S_LEN + trow)) * DKV + hk * 64 + tq;
    kp0 = *(const uint4*)gk; kp1 = *(const uint4*)(gk + 8);
    const unsigned short* gv = Vt + ((size_t)(bb * DKV + hk * 64 + trow)) * S_LEN + tq;
    vp0 = *(const uint4*)gv; vp1 = *(const uint4*)(gv + 8);
  }

  f32x4 Oacc[2][4] = {};                // [tile][dt]; O^T: col = q-row, row = d
  float lacc0 = 0.f, lacc1 = 0.f;

  const int tmax = qt1;
  for (int t = 0; t <= tmax; ++t) {
    const int bs = t & 1;
    // write tile t (regs -> LDS); compiler inserts the precise vmcnt wait for kp/vp here
    *(uint4*)&Ks[bs][trow * 72 + tq]      = kp0;
    *(uint4*)&Ks[bs][trow * 72 + tq + 8]  = kp1;
    *(uint4*)&Vts[bs][trow * 72 + tq]     = vp0;
    *(uint4*)&Vts[bs][trow * 72 + tq + 8] = vp1;
    if (t < tmax) {                     // prefetch tile t+1 (stays in flight across barrier)
      const int t1 = (t + 1) * 64;
      const unsigned short* gk = K + ((size_t)(bb * S_LEN + t1 + trow)) * DKV + hk * 64 + tq;
      kp0 = *(const uint4*)gk; kp1 = *(const uint4*)(gk + 8);
      const unsigned short* gv = Vt + ((size_t)(bb * DKV + hk * 64 + trow)) * S_LEN + t1 + tq;
      vp0 = *(const uint4*)gv; vp1 = *(const uint4*)(gv + 8);
    }
    asm volatile("s_waitcnt lgkmcnt(0)" ::: "memory");  // my ds_writes done (NOT vmcnt)
    __builtin_amdgcn_s_barrier();                       // raw barrier: no vmcnt drain
    __builtin_amdgcn_sched_barrier(0);

    const bool a0 = (t <= qt0);         // tile1 is active for the whole loop

    // ---- S phase: each kf b128 read feeds both active tiles ----
    f32x4 S0[4] = {}, S1[4] = {};
    __builtin_amdgcn_s_setprio(1);
#pragma unroll
    for (int ks = 0; ks < 2; ++ks)
#pragma unroll
      for (int nt = 0; nt < 4; ++nt) {
        const short8 kf = *(const short8*)&Ks[bs][(nt * 16 + lcol) * 72 + ks * 32 + lq * 8];
        const short8 q0 = ks ? qf01 : qf00;
        const short8 q1 = ks ? qf11 : qf10;
        if (a0) S0[nt] = __builtin_amdgcn_mfma_f32_16x16x32_bf16(kf, q0, S0[nt], 0, 0, 0);
        S1[nt] = __builtin_amdgcn_mfma_f32_16x16x32_bf16(kf, q1, S1[nt], 0, 0, 0);
      }
    __builtin_amdgcn_s_setprio(0);

    // ---- diagonal masks (local coords: mask key-offset > prow) ----
    if (t == qt0) {
#pragma unroll
      for (int nt = 0; nt < 4; ++nt)
#pragma unroll
        for (int r = 0; r < 4; ++r)
          if (nt * 16 + lq * 4 + r > prow) S0[nt][r] = -1e30f;
    }
    if (t == qt1) {
#pragma unroll
      for (int nt = 0; nt < 4; ++nt)
#pragma unroll
        for (int r = 0; r < 4; ++r)
          if (nt * 16 + lq * 4 + r > prow) S1[nt][r] = -1e30f;
    }

    // ---- softmax + in-register P redistribution (no LDS round-trip) ----
    short8 pf00, pf01, pf10, pf11;
    if (a0) SOFTMAX_FRAG(S0, lacc0, pf0);
    SOFTMAX_FRAG(S1, lacc1, pf1);

    // ---- O phase: each vf b128 read feeds both active tiles ----
    __builtin_amdgcn_s_setprio(1);
#pragma unroll
    for (int ks = 0; ks < 2; ++ks)
#pragma unroll
      for (int dt = 0; dt < 4; ++dt) {
        const short8 vf = *(const short8*)&Vts[bs][(dt * 16 + lcol) * 72 + ks * 32 + lq * 8];
        const short8 p0 = ks ? pf01 : pf00;
        const short8 p1 = ks ? pf11 : pf10;
        if (a0) Oacc[0][dt] = __builtin_amdgcn_mfma_f32_16x16x32_bf16(vf, p0, Oacc[0][dt], 0, 0, 0);
        Oacc[1][dt] = __builtin_amdgcn_mfma_f32_16x16x32_bf16(vf, p1, Oacc[1][dt], 0, 0, 0);
      }
    __builtin_amdgcn_s_setprio(0);
  }

  // epilogue: reduce l across lq (2 shuffles per tile), normalize, store
  const int qts[2] = {qt0, qt1};
  const float laccs[2] = {lacc0, lacc1};
#pragma unroll
  for (int j = 0; j < 2; ++j) {
    float l = laccs[j];
    l += __shfl_xor(l, 16);
    l += __shfl_xor(l, 32);
    const float inv = 1.0f / l;
    const int qrow = qts[j] * 64 + prow;
#pragma unroll
    for (int dt = 0; dt < 4; ++dt) {
      unsigned short u[4] = {f2bf(Oacc[j][dt][0] * inv), f2bf(Oacc[j][dt][1] * inv),
                             f2bf(Oacc[j][dt][2] * inv), f2bf(Oacc[j][dt][3] * inv)};
      *(uint2*)&O[(size_t)(bb * S_LEN + qrow) * D_MODEL + hq * 64 + dt * 16 + lq * 4] =
          *(const uint2*)u;
    }
  }
}

extern "C" void kernel_launch(void* const* d_in, const int* in_sizes, int n_in,
                              void* d_out, int out_size, void* d_ws, size_t ws_size,
                              hipStream_t stream) {
  const float* x  = (const float*)d_in[0];   // fp32 inputs per the reference dtypes
  const float* Wq = (const float*)d_in[1];
  const float* Wk = (const float*)d_in[2];
  const float* Wv = (const float*)d_in[3];
  const float* Wo = (const float*)d_in[4];
  float* out = (float*)d_out;                // fp32 output per the reference

  // Workspace (bf16 elements), total ~70 MiB:
  unsigned short* Qb  = (unsigned short*)d_ws;                 // 4096 x 2048
  unsigned short* Kb  = Qb  + (size_t)4096 * 2048;             // 4096 x 512
  unsigned short* Vtg = Kb  + (size_t)4096 * 512;              // 1024 x 2048 (V pre-transposed)
  unsigned short* Ab  = Vtg + (size_t)1024 * 2048;             // 4096 x 2048
  unsigned short* xb  = Ab  + (size_t)4096 * 2048;             // 4096 x 2048
  unsigned short* Wqb = xb  + (size_t)4096 * 2048;             // 2048 x 2048
  unsigned short* Wkb = Wqb + (size_t)2048 * 2048;             // 512 x 2048
  unsigned short* Wvb = Wkb + (size_t)512 * 2048;              // 512 x 2048
  unsigned short* Wob = Wvb + (size_t)512 * 2048;              // 2048 x 2048

  static bool attr_set = false;
  if (!attr_set) {
    hipFuncSetAttribute(reinterpret_cast<const void*>(qkv_gemm_kernel),
                        hipFuncAttributeMaxDynamicSharedMemorySize, 131072);
    hipFuncSetAttribute(reinterpret_cast<const void*>(oproj_gemm_kernel),
                        hipFuncAttributeMaxDynamicSharedMemorySize, 98304);
    attr_set = true;
  }

  cvt_all_kernel<<<9216, 256, 0, stream>>>(x, Wq, Wk, Wv, Wo, xb, Wqb, Wkb, Wvb, Wob);

  qkv_gemm_kernel<<<192, 512, 131072, stream>>>(xb, Wqb, Wkb, Wvb, Qb, Kb, Vtg);
  rope_both_kernel<<<20480, 256, 0, stream>>>(Qb, Kb);
  attn_kernel<<<dim3(16, 32, 2), 256, 0, stream>>>(Qb, Kb, Vtg, Ab);
  oproj_gemm_kernel<<<256, 512, 98304, stream>>>(Ab, Wob, out);
}

// Round 6
// 285.256 us; speedup vs baseline: 1.7391x; 1.7391x over previous
//
#include <hip/hip_runtime.h>
#include <stdint.h>

// Problem constants (fixed by the reference): B=2, S=2048, D=2048, Dh=64, Hq=32, Hkv=8, G=4.
#define S_LEN   2048
#define D_MODEL 2048
#define DKV     512

typedef __attribute__((ext_vector_type(8))) short short8;   // 8 x bf16
typedef __attribute__((ext_vector_type(4))) float f32x4;
typedef __attribute__((ext_vector_type(4))) unsigned uint4v;

__device__ static inline unsigned short f2bf(float f) {     // RNE float->bf16 (finite values)
  unsigned u = __builtin_bit_cast(unsigned, f);
  u += 0x7FFFu + ((u >> 16) & 1u);
  return (unsigned short)(u >> 16);
}
__device__ static inline float bf2f(unsigned short h) {
  return __builtin_bit_cast(float, ((unsigned)h) << 16);
}
// pack hi16(f0), hi16(f1) -> one dword (bf16 truncation; 1 v_perm_b32)
__device__ static inline unsigned packtrunc2(float f0, float f1) {
  return __builtin_amdgcn_perm(__builtin_bit_cast(unsigned, f1),
                               __builtin_bit_cast(unsigned, f0), 0x07060302u);
}

__device__ static inline void gload_lds16(const void* g, void* lds) {
  __builtin_amdgcn_global_load_lds((const __attribute__((address_space(1))) void*)g,
                                   (__attribute__((address_space(3))) void*)lds,
                                   16, 0, 0);
}

template <int N>
__device__ __forceinline__ void wait_vm() {
  if constexpr (N == 8)      asm volatile("s_waitcnt vmcnt(8)" ::: "memory");
  else if constexpr (N == 6) asm volatile("s_waitcnt vmcnt(6)" ::: "memory");
  else if constexpr (N == 4) asm volatile("s_waitcnt vmcnt(4)" ::: "memory");
  else if constexpr (N == 3) asm volatile("s_waitcnt vmcnt(3)" ::: "memory");
  else                       asm volatile("s_waitcnt vmcnt(0)" ::: "memory");
}

// gfx950 conditional-exchange primitives (register-pair <-> lane-half swaps):
__device__ static inline void pl32swap(unsigned& a, unsigned& b) {
  asm volatile("v_permlane32_swap_b32 %0, %1" : "+v"(a), "+v"(b));
}
__device__ static inline void pl16swap(unsigned& a, unsigned& b) {
  asm volatile("v_permlane16_swap_b32 %0, %1" : "+v"(a), "+v"(b));
}

// fp32 -> bf16 bulk conversion for all 5 inputs in ONE launch (exact region split, units of 8 floats).
__global__ __launch_bounds__(256) void cvt_all_kernel(
    const float* __restrict__ x, const float* __restrict__ wq, const float* __restrict__ wk,
    const float* __restrict__ wv, const float* __restrict__ wo,
    unsigned short* __restrict__ xb, unsigned short* __restrict__ wqb,
    unsigned short* __restrict__ wkb, unsigned short* __restrict__ wvb,
    unsigned short* __restrict__ wob) {
  int i = blockIdx.x * 256 + threadIdx.x;          // 0 .. 2359296-1
  const float* s; unsigned short* d;
  if (i < 1048576)      { s = x;  d = xb;  }
  else if (i < 1572864) { s = wq; d = wqb; i -= 1048576; }
  else if (i < 1703936) { s = wk; d = wkb; i -= 1572864; }
  else if (i < 1835008) { s = wv; d = wvb; i -= 1703936; }
  else                  { s = wo; d = wob; i -= 1835008; }
  const float4 a = ((const float4*)s)[i * 2];
  const float4 b = ((const float4*)s)[i * 2 + 1];
  unsigned short u[8] = {f2bf(a.x), f2bf(a.y), f2bf(a.z), f2bf(a.w),
                         f2bf(b.x), f2bf(b.y), f2bf(b.z), f2bf(b.w)};
  *(uint4*)(d + (size_t)i * 8) = *(const uint4*)u;
}

// ---------------------------------------------------------------------------------------------
// Deep-pipelined GEMM: C(M,N) = A(M,K=2048) @ B(N,K)^T, bf16 inputs.  (unchanged from R1)
// ---------------------------------------------------------------------------------------------
template <int BM, int CMODE, typename CT>
__device__ __forceinline__ void gemm_deep_body(
    const unsigned short* __restrict__ A, int lda,
    const unsigned short* __restrict__ B, int ldb,
    CT* __restrict__ C, int ldc, int m0, int n0, unsigned short* ldsu) {
  constexpr int MI = BM / 32;             // 8 (BM=256) or 4 (BM=128)
  constexpr int NI = 4;
  constexpr int A_BYTES = BM * 64;        // BM*32*2B : 16KB or 8KB
  constexpr int B_BYTES = 256 * 64;       // 16KB
  constexpr int TILE_BYTES = A_BYTES + B_BYTES;
  constexpr int AL = BM / 128;            // A stage-loads per thread per phase: 2 or 1
  constexpr int LOADS = AL + 2;           // total stage-loads/thread/phase: 4 or 3
  constexpr int VMS = 2 * LOADS;          // steady-state vmcnt (retire 3-phases-old tile)

  const int tid  = threadIdx.x;
  const int lane = tid & 63;
  const int w    = tid >> 6;              // 0..7
  const int wm   = w >> 2;                // 0..1  (M halves)
  const int wn   = w & 3;                 // 0..3  (N quarters)
  const int lcol = lane & 15;
  const int lq   = lane >> 4;
  char* const ldsb = (char*)ldsu;

  // ---- staging lane constants (inverse swizzle on the global side) ----
  const int sl   = (lane & 7) ^ (lane >> 3);   // logical slab this lane must fetch
  const int colg = (sl & 3) * 8;               // element col within the 32-wide K-tile
  const unsigned short* gA[AL];
  const unsigned short* gB[2];
#pragma unroll
  for (int L = 0; L < AL; ++L) {
    const int r = 2 * (L * 64 + w * 8 + (lane >> 3)) + (sl >> 2);
    gA[L] = A + (size_t)(m0 + r) * lda + colg;
  }
#pragma unroll
  for (int L = 0; L < 2; ++L) {
    const int r = 2 * (L * 64 + w * 8 + (lane >> 3)) + (sl >> 2);
    gB[L] = B + (size_t)(n0 + r) * ldb + colg;
  }

  auto stage = [&](int tt) {
    char* const sb = ldsb + (tt & 3) * TILE_BYTES;
#pragma unroll
    for (int L = 0; L < AL; ++L)
      gload_lds16(gA[L] + tt * 32, sb + L * 8192 + w * 1024);
#pragma unroll
    for (int L = 0; L < 2; ++L)
      gload_lds16(gB[L] + tt * 32, sb + A_BYTES + L * 8192 + w * 1024);
  };

  // ---- fragment-read lane constant (swizzled) ----
  const int sR    = (((lcol & 1) << 2) | lq) ^ ((lcol >> 1) & 7);
  const int rdoff = (lcol >> 1) * 128 + sR * 16;

  f32x4 acc[MI][NI] = {};

  auto compute_tile = [&](char* buf) {
    short8 af[MI], bfr[NI];
#pragma unroll
    for (int mi = 0; mi < MI; ++mi)
      af[mi] = *(const short8*)(buf + wm * (MI * 1024) + mi * 1024 + rdoff);
#pragma unroll
    for (int ni = 0; ni < NI; ++ni)
      bfr[ni] = *(const short8*)(buf + A_BYTES + wn * 4096 + ni * 1024 + rdoff);
    __builtin_amdgcn_s_setprio(1);
#pragma unroll
    for (int mi = 0; mi < MI; ++mi)
#pragma unroll
      for (int ni = 0; ni < NI; ++ni)
        acc[mi][ni] = __builtin_amdgcn_mfma_f32_16x16x32_bf16(af[mi], bfr[ni], acc[mi][ni], 0, 0, 0);
    __builtin_amdgcn_s_setprio(0);
  };

  // prologue: 3 tiles in flight
  stage(0); stage(1); stage(2);

#define GPHASE(T, VMW, DOSTG)                          \
  do {                                                 \
    wait_vm<VMW>();                                    \
    __builtin_amdgcn_s_barrier();                      \
    asm volatile("" ::: "memory");                     \
    __builtin_amdgcn_sched_barrier(0);                 \
    if (DOSTG) stage((T) + 3);                         \
    compute_tile(ldsb + ((T) & 3) * TILE_BYTES);       \
  } while (0)

  for (int t4 = 0; t4 < 15; ++t4) {
    const int t = t4 * 4;
    GPHASE(t + 0, VMS, true);
    GPHASE(t + 1, VMS, true);
    GPHASE(t + 2, VMS, true);
    GPHASE(t + 3, VMS, true);
  }
  GPHASE(60, VMS,   true);
  GPHASE(61, VMS,   false);
  GPHASE(62, LOADS, false);
  GPHASE(63, 0,     false);
#undef GPHASE

  // epilogue (m97-verified C/D mapping, generalized)
#pragma unroll
  for (int mi = 0; mi < MI; ++mi)
#pragma unroll
    for (int ni = 0; ni < NI; ++ni)
#pragma unroll
      for (int r = 0; r < 4; ++r) {
        const int row = m0 + wm * (MI * 16) + mi * 16 + lq * 4 + r;
        const int col = n0 + wn * 64 + ni * 16 + lcol;
        if constexpr (CMODE == 1) {
          C[((size_t)((row >> 11) * 512 + col)) * 2048 + (row & 2047)] = f2bf(acc[mi][ni][r]);
        } else if constexpr (CMODE == 2) {
          C[(size_t)row * ldc + col] = acc[mi][ni][r];
        } else {
          C[(size_t)row * ldc + col] = f2bf(acc[mi][ni][r]);
        }
      }
}

// Fused QKV projection: 192 blocks (16 M-tiles x [8 Q + 2 K + 2 V] N-tiles), 512 thr, 128KB LDS.
__global__ __launch_bounds__(512, 2) void qkv_gemm_kernel(
    const unsigned short* __restrict__ x,
    const unsigned short* __restrict__ Wq, const unsigned short* __restrict__ Wk,
    const unsigned short* __restrict__ Wv,
    unsigned short* __restrict__ Qo, unsigned short* __restrict__ Ko,
    unsigned short* __restrict__ Vt) {
  extern __shared__ __align__(16) unsigned short lds[];
  const int bid = blockIdx.x;                   // 192 = 8 XCDs * 24
  const int swz = (bid & 7) * 24 + (bid >> 3);  // bijective XCD swizzle (192 % 8 == 0)
  const int mt = swz / 12, nt = swz % 12;
  const int m0 = mt * 256;
  if (nt < 8)
    gemm_deep_body<256, 0, unsigned short>(x, D_MODEL, Wq, D_MODEL, Qo, D_MODEL, m0, nt * 256, lds);
  else if (nt < 10)
    gemm_deep_body<256, 0, unsigned short>(x, D_MODEL, Wk, D_MODEL, Ko, DKV, m0, (nt - 8) * 256, lds);
  else
    gemm_deep_body<256, 1, unsigned short>(x, D_MODEL, Wv, D_MODEL, Vt, DKV, m0, (nt - 10) * 256, lds);
}

// O-projection: bf16 A (attn out) x bf16 Wo -> fp32 out. 256 blocks (32 x 8) = exact CU fill.
__global__ __launch_bounds__(512, 2) void oproj_gemm_kernel(
    const unsigned short* __restrict__ A, const unsigned short* __restrict__ Wo,
    float* __restrict__ C) {
  extern __shared__ __align__(16) unsigned short lds[];
  const int bid = blockIdx.x;                   // 256 = 8 XCDs * 32
  const int swz = (bid & 7) * 32 + (bid >> 3);
  const int mt = swz >> 3, nt = swz & 7;
  gemm_deep_body<128, 2, float>(A, D_MODEL, Wo, D_MODEL, C, D_MODEL, mt * 128, nt * 256, lds);
}

// RoPE in-place on ws Q and K in ONE launch (row = b*S+s, col = h*64+d; interleaved pairs).
// Q scale folds 1/sqrt(Dh)*log2(e) = 0.125*1.442695 (log2-domain softmax downstream).
__global__ __launch_bounds__(256) void rope_both_kernel(unsigned short* __restrict__ Qb,
                                                        unsigned short* __restrict__ Kb) {
  int idx = blockIdx.x * 256 + threadIdx.x;       // 0 .. 5242879
  unsigned short* X; int lgHalf; float scale;
  if (idx < 4194304) { X = Qb; lgHalf = 10; scale = 0.1803368801111244f; }
  else               { X = Kb; lgHalf = 8;  scale = 1.0f; idx -= 4194304; }
  const int half = 1 << lgHalf;
  const int r  = idx >> lgHalf;
  const int cp = idx & (half - 1);
  const int i  = cp & 31;
  const int s  = r & (S_LEN - 1);
  const float inv = exp2f(-13.287712379549449f * (float)(2 * i) * (1.0f / 64.0f)); // 10000^(-2i/64)
  const float th  = (float)s * inv;
  const float c = cosf(th), sn = sinf(th);
  unsigned short* p = X + ((size_t)r << (lgHalf + 1)) + 2 * cp;
  const float x0 = bf2f(p[0]), x1 = bf2f(p[1]);
  p[0] = f2bf((x0 * c - x1 * sn) * scale);
  p[1] = f2bf((x0 * sn + x1 * c) * scale);
}

// ---------------------------------------------------------------------------------------------
// Flash attention (R6 = R4 deferred-PV body at the ONLY safe launch bounds (256,2)):
//  - R4's deferred-PV structure passed correctness; it died from launch-bounds spill only.
//    Empirical VGPR law on this compiler (R2-R5 A/B): cap = 512/(2*minwaves):
//    Y=2 -> 128 (fits, 92 VGPR); Y=3 -> 85 (spill); Y=4 -> 64 (catastrophic spill).
//  - Pipeline per iter t: stage K(t) -> lgkm+barrier -> S-MFMA(t) -> stage V(t) ->
//    mask -> O-MFMA(t-1) [Vts[bs^1], pf(t-1)] -> softmax(t) -> pf.
//    O(t-1) MFMAs are independent of softmax(t) VALU -> in-wave ILP overlap (the only
//    available lever at 2 waves/SIMD).
//  - setprio(1) around S and deferred-O MFMA clusters (T5; blocks unsynced).
//  - Race check (1 barrier/iter) re-verified: V(t) writes Vts[bs] after barrier(t); that
//    buffer's last reads (O(t-2) in iter t-1) precede barrier(t). O(t-1) reads Vts[bs^1]
//    before barrier(t+1); next writes to it follow barrier(t+1). K writes/reads same as R3.
// ---------------------------------------------------------------------------------------------
#define SOFTMAX_FRAG(Sv, lac, pf)                                              \
  do {                                                                         \
    float e0 = __builtin_amdgcn_exp2f(Sv[0][0]);                               \
    float e1 = __builtin_amdgcn_exp2f(Sv[0][1]);                               \
    float e2 = __builtin_amdgcn_exp2f(Sv[0][2]);                               \
    float e3 = __builtin_amdgcn_exp2f(Sv[0][3]);                               \
    unsigned dd0 = packtrunc2(e0, e1), dd1 = packtrunc2(e2, e3);               \
    lac += (e0 + e1) + (e2 + e3);                                              \
    e0 = __builtin_amdgcn_exp2f(Sv[1][0]);                                     \
    e1 = __builtin_amdgcn_exp2f(Sv[1][1]);                                     \
    e2 = __builtin_amdgcn_exp2f(Sv[1][2]);                                     \
    e3 = __builtin_amdgcn_exp2f(Sv[1][3]);                                     \
    unsigned dd2 = packtrunc2(e0, e1), dd3 = packtrunc2(e2, e3);               \
    lac += (e0 + e1) + (e2 + e3);                                              \
    e0 = __builtin_amdgcn_exp2f(Sv[2][0]);                                     \
    e1 = __builtin_amdgcn_exp2f(Sv[2][1]);                                     \
    e2 = __builtin_amdgcn_exp2f(Sv[2][2]);                                     \
    e3 = __builtin_amdgcn_exp2f(Sv[2][3]);                                     \
    unsigned dd4 = packtrunc2(e0, e1), dd5 = packtrunc2(e2, e3);               \
    lac += (e0 + e1) + (e2 + e3);                                              \
    e0 = __builtin_amdgcn_exp2f(Sv[3][0]);                                     \
    e1 = __builtin_amdgcn_exp2f(Sv[3][1]);                                     \
    e2 = __builtin_amdgcn_exp2f(Sv[3][2]);                                     \
    e3 = __builtin_amdgcn_exp2f(Sv[3][3]);                                     \
    unsigned dd6 = packtrunc2(e0, e1), dd7 = packtrunc2(e2, e3);               \
    lac += (e0 + e1) + (e2 + e3);                                              \
    pl32swap(dd0, dd2); pl32swap(dd1, dd3);                                    \
    pl32swap(dd4, dd6); pl32swap(dd5, dd7);                                    \
    pl16swap(dd0, dd2); pl16swap(dd1, dd3);                                    \
    pl16swap(dd4, dd6); pl16swap(dd5, dd7);                                    \
    const uint4v va_ = {dd0, dd1, dd2, dd3};                                   \
    const uint4v vb_ = {dd4, dd5, dd6, dd7};                                   \
    pf##0 = __builtin_bit_cast(short8, va_);                                   \
    pf##1 = __builtin_bit_cast(short8, vb_);                                   \
  } while (0)

__global__ __launch_bounds__(256, 2) void attn_kernel(const unsigned short* __restrict__ Q,
                                                      const unsigned short* __restrict__ K,
                                                      const unsigned short* __restrict__ Vt,
                                                      unsigned short* __restrict__ O) {
  const int hq = blockIdx.y;
  const int bb = blockIdx.z;
  const int hk = hq >> 2;
  const int tid  = threadIdx.x;
  const int lane = tid & 63;
  const int w    = tid >> 6;
  const int lcol = lane & 15;
  const int lq   = lane >> 4;
  const int trow = tid >> 2;            // staging row 0..63
  const int tq   = (tid & 3) * 16;      // staging col quarter (16 elems = 32B)

  const int X   = blockIdx.x;           // 0..15
  const int qt0 = X, qt1 = 31 - X;      // ascending; updates = (X+1)+(32-X) = 33 uniform

  // 72-elem rows (144B): 16B-aligned, 2-way bank aliasing on b128 ops (free, m136).
  __shared__ unsigned short Ks[2][64 * 72];
  __shared__ unsigned short Vts[2][64 * 72];

  const int prow = w * 16 + lcol;       // this lane's q-row within a 64-row tile

  // ---- Q fragments direct from global: B-frag n=prow, k = ks*32+lq*8 (16B contiguous) ----
  short8 qf00, qf01, qf10, qf11;
  {
    const unsigned short* g0 = Q + ((size_t)(bb * S_LEN + qt0 * 64 + prow)) * D_MODEL + hq * 64;
    const unsigned short* g1 = Q + ((size_t)(bb * S_LEN + qt1 * 64 + prow)) * D_MODEL + hq * 64;
    qf00 = *(const short8*)(g0 + lq * 8);
    qf01 = *(const short8*)(g0 + 32 + lq * 8);
    qf10 = *(const short8*)(g1 + lq * 8);
    qf11 = *(const short8*)(g1 + 32 + lq * 8);
  }

  // ---- prefetch K/V tile 0 into registers ----
  uint4 kp0, kp1, vp0, vp1;
  {
    const unsigned short* gk = K + ((size_t)(bb * S_LEN + trow)) * DKV + hk * 64 + tq;
    kp0 = *(const uint4*)gk; kp1 = *(const uint4*)(gk + 8);
    const unsigned short* gv = Vt + ((size_t)(bb * DKV + hk * 64 + trow)) * S_LEN + tq;
    vp0 = *(const uint4*)gv; vp1 = *(const uint4*)(gv + 8);
  }

  f32x4 Oacc[2][4] = {};                // [tile][dt]; O^T: col = q-row, row = d
  float lacc0 = 0.f, lacc1 = 0.f;
  short8 pf00 = {}, pf01 = {}, pf10 = {}, pf11 = {};   // deferred P fragments (iter t-1)

  const int tmax = qt1;
  for (int t = 0; t <= tmax; ++t) {
    const int bs = t & 1;
    // ---- stage K(t); prefetch K(t+1) ----
    *(uint4*)&Ks[bs][trow * 72 + tq]     = kp0;
    *(uint4*)&Ks[bs][trow * 72 + tq + 8] = kp1;
    if (t < tmax) {
      const int t1 = (t + 1) * 64;
      const unsigned short* gk = K + ((size_t)(bb * S_LEN + t1 + trow)) * DKV + hk * 64 + tq;
      kp0 = *(const uint4*)gk; kp1 = *(const uint4*)(gk + 8);
    }
    asm volatile("s_waitcnt lgkmcnt(0)" ::: "memory");  // my ds_writes done (NOT vmcnt)
    __builtin_amdgcn_s_barrier();                       // raw barrier: no vmcnt drain
    __builtin_amdgcn_sched_barrier(0);

    const bool a0 = (t <= qt0);         // tile1 active for the whole loop

    // ---- S phase: MFMA S(t) from Ks[bs] ----
    f32x4 S0[4] = {}, S1[4] = {};
    __builtin_amdgcn_s_setprio(1);
#pragma unroll
    for (int ks = 0; ks < 2; ++ks)
#pragma unroll
      for (int nt = 0; nt < 4; ++nt) {
        const short8 kf = *(const short8*)&Ks[bs][(nt * 16 + lcol) * 72 + ks * 32 + lq * 8];
        const short8 q0 = ks ? qf01 : qf00;
        const short8 q1 = ks ? qf11 : qf10;
        if (a0) S0[nt] = __builtin_amdgcn_mfma_f32_16x16x32_bf16(kf, q0, S0[nt], 0, 0, 0);
        S1[nt] = __builtin_amdgcn_mfma_f32_16x16x32_bf16(kf, q1, S1[nt], 0, 0, 0);
      }
    __builtin_amdgcn_s_setprio(0);

    // ---- stage V(t) AFTER the barrier (buffer's prior reads all pre-date barrier(t)) ----
    *(uint4*)&Vts[bs][trow * 72 + tq]     = vp0;
    *(uint4*)&Vts[bs][trow * 72 + tq + 8] = vp1;
    if (t < tmax) {
      const int t1 = (t + 1) * 64;
      const unsigned short* gv = Vt + ((size_t)(bb * DKV + hk * 64 + trow)) * S_LEN + t1 + tq;
      vp0 = *(const uint4*)gv; vp1 = *(const uint4*)(gv + 8);
    }

    // ---- diagonal masks (local coords: mask key-offset > prow) ----
    if (t == qt0) {
#pragma unroll
      for (int nt = 0; nt < 4; ++nt)
#pragma unroll
        for (int r = 0; r < 4; ++r)
          if (nt * 16 + lq * 4 + r > prow) S0[nt][r] = -1e30f;
    }
    if (t == qt1) {
#pragma unroll
      for (int nt = 0; nt < 4; ++nt)
#pragma unroll
        for (int r = 0; r < 4; ++r)
          if (nt * 16 + lq * 4 + r > prow) S1[nt][r] = -1e30f;
    }

    // ---- deferred O phase (t-1): reads Vts[bs^1] + pf(t-1); independent of softmax(t) ----
    if (t > 0) {
      const bool a0p = (t - 1 <= qt0);
      __builtin_amdgcn_s_setprio(1);
#pragma unroll
      for (int ks = 0; ks < 2; ++ks)
#pragma unroll
        for (int dt = 0; dt < 4; ++dt) {
          const short8 vf = *(const short8*)&Vts[bs ^ 1][(dt * 16 + lcol) * 72 + ks * 32 + lq * 8];
          const short8 p0 = ks ? pf01 : pf00;
          const short8 p1 = ks ? pf11 : pf10;
          if (a0p) Oacc[0][dt] = __builtin_amdgcn_mfma_f32_16x16x32_bf16(vf, p0, Oacc[0][dt], 0, 0, 0);
          Oacc[1][dt] = __builtin_amdgcn_mfma_f32_16x16x32_bf16(vf, p1, Oacc[1][dt], 0, 0, 0);
        }
      __builtin_amdgcn_s_setprio(0);
    }

    // ---- softmax(t) -> pf (after O consumed the old pf; VALU overlaps O's MFMAs) ----
    if (a0) SOFTMAX_FRAG(S0, lacc0, pf0);
    SOFTMAX_FRAG(S1, lacc1, pf1);
  }

  // ---- drain: final O(tmax), tile1 only (qt0 < qt1 always) ----
  asm volatile("s_waitcnt lgkmcnt(0)" ::: "memory");
  __builtin_amdgcn_s_barrier();       // all waves' V(tmax) writes visible
#pragma unroll
  for (int ks = 0; ks < 2; ++ks)
#pragma unroll
    for (int dt = 0; dt < 4; ++dt) {
      const short8 vf = *(const short8*)&Vts[tmax & 1][(dt * 16 + lcol) * 72 + ks * 32 + lq * 8];
      const short8 p1 = ks ? pf11 : pf10;
      Oacc[1][dt] = __builtin_amdgcn_mfma_f32_16x16x32_bf16(vf, p1, Oacc[1][dt], 0, 0, 0);
    }

  // epilogue: reduce l across lq (2 shuffles per tile), normalize, store
  const int qts[2] = {qt0, qt1};
  const float laccs[2] = {lacc0, lacc1};
#pragma unroll
  for (int j = 0; j < 2; ++j) {
    float l = laccs[j];
    l += __shfl_xor(l, 16);
    l += __shfl_xor(l, 32);
    const float inv = 1.0f / l;
    const int qrow = qts[j] * 64 + prow;
#pragma unroll
    for (int dt = 0; dt < 4; ++dt) {
      unsigned short u[4] = {f2bf(Oacc[j][dt][0] * inv), f2bf(Oacc[j][dt][1] * inv),
                             f2bf(Oacc[j][dt][2] * inv), f2bf(Oacc[j][dt][3] * inv)};
      *(uint2*)&O[(size_t)(bb * S_LEN + qrow) * D_MODEL + hq * 64 + dt * 16 + lq * 4] =
          *(const uint2*)u;
    }
  }
}

extern "C" void kernel_launch(void* const* d_in, const int* in_sizes, int n_in,
                              void* d_out, int out_size, void* d_ws, size_t ws_size,
                              hipStream_t stream) {
  const float* x  = (const float*)d_in[0];   // fp32 inputs per the reference dtypes
  const float* Wq = (const float*)d_in[1];
  const float* Wk = (const float*)d_in[2];
  const float* Wv = (const float*)d_in[3];
  const float* Wo = (const float*)d_in[4];
  float* out = (float*)d_out;                // fp32 output per the reference

  // Workspace (bf16 elements), total ~70 MiB:
  unsigned short* Qb  = (unsigned short*)d_ws;                 // 4096 x 2048
  unsigned short* Kb  = Qb  + (size_t)4096 * 2048;             // 4096 x 512
  unsigned short* Vtg = Kb  + (size_t)4096 * 512;              // 1024 x 2048 (V pre-transposed)
  unsigned short* Ab  = Vtg + (size_t)1024 * 2048;             // 4096 x 2048
  unsigned short* xb  = Ab  + (size_t)4096 * 2048;             // 4096 x 2048
  unsigned short* Wqb = xb  + (size_t)4096 * 2048;             // 2048 x 2048
  unsigned short* Wkb = Wqb + (size_t)2048 * 2048;             // 512 x 2048
  unsigned short* Wvb = Wkb + (size_t)512 * 2048;              // 512 x 2048
  unsigned short* Wob = Wvb + (size_t)512 * 2048;              // 2048 x 2048

  static bool attr_set = false;
  if (!attr_set) {
    hipFuncSetAttribute(reinterpret_cast<const void*>(qkv_gemm_kernel),
                        hipFuncAttributeMaxDynamicSharedMemorySize, 131072);
    hipFuncSetAttribute(reinterpret_cast<const void*>(oproj_gemm_kernel),
                        hipFuncAttributeMaxDynamicSharedMemorySize, 98304);
    attr_set = true;
  }

  cvt_all_kernel<<<9216, 256, 0, stream>>>(x, Wq, Wk, Wv, Wo, xb, Wqb, Wkb, Wvb, Wob);

  qkv_gemm_kernel<<<192, 512, 131072, stream>>>(xb, Wqb, Wkb, Wvb, Qb, Kb, Vtg);
  rope_both_kernel<<<20480, 256, 0, stream>>>(Qb, Kb);
  attn_kernel<<<dim3(16, 32, 2), 256, 0, stream>>>(Qb, Kb, Vtg, Ab);
  oproj_gemm_kernel<<<256, 512, 98304, stream>>>(Ab, Wob, out);
}